// Round 2
// baseline (90.795 us; speedup 1.0000x reference)
//
#include <hip/hip_runtime.h>

#define Nn 768
#define Dd 128
#define LDP 136   // padded LDS row length in bf16 elems (272 B, 16B-aligned)

typedef __attribute__((ext_vector_type(8))) short bf16x8;
typedef __attribute__((ext_vector_type(4))) float f32x4;
typedef __attribute__((ext_vector_type(4))) int   i32x4;

static __device__ __forceinline__ unsigned short f2bf(float f) {
  unsigned int u = __builtin_bit_cast(unsigned int, f);
  u += 0x7fffu + ((u >> 16) & 1u);   // RNE
  return (unsigned short)(u >> 16);
}
static __device__ __forceinline__ float bf2f(unsigned short h) {
  unsigned int u = ((unsigned int)h) << 16;
  return __builtin_bit_cast(float, u);
}

// left[i][e] = sum_d x[i][d] * W_in[e][d] + b_in[e], stored bf16
__global__ __launch_bounds__(128)
void k_left(const float* __restrict__ x, const float* __restrict__ Win,
            const float* __restrict__ bin, unsigned short* __restrict__ left) {
  __shared__ float sx[Dd];
  const int i = blockIdx.x;
  const int e = threadIdx.x;
  sx[e] = x[i * Dd + e];
  __syncthreads();
  const float4* wrow = (const float4*)(Win + e * Dd);
  // 4 independent partial accumulators to break the FMA dependency chain
  float a0 = 0.f, a1 = 0.f, a2 = 0.f, a3 = 0.f;
#pragma unroll
  for (int d4 = 0; d4 < Dd / 4; d4 += 4) {
    float4 w0 = wrow[d4+0], w1 = wrow[d4+1], w2 = wrow[d4+2], w3 = wrow[d4+3];
    a0 += sx[4*d4+ 0]*w0.x + sx[4*d4+ 1]*w0.y + sx[4*d4+ 2]*w0.z + sx[4*d4+ 3]*w0.w;
    a1 += sx[4*d4+ 4]*w1.x + sx[4*d4+ 5]*w1.y + sx[4*d4+ 6]*w1.z + sx[4*d4+ 7]*w1.w;
    a2 += sx[4*d4+ 8]*w2.x + sx[4*d4+ 9]*w2.y + sx[4*d4+10]*w2.z + sx[4*d4+11]*w2.w;
    a3 += sx[4*d4+12]*w3.x + sx[4*d4+13]*w3.y + sx[4*d4+14]*w3.z + sx[4*d4+15]*w3.w;
  }
  left[i * Dd + e] = f2bf(((a0 + a1) + (a2 + a3)) + bin[e]);
}

// out[i, j, e] = sum_d (W_out[e][d] * left[i][d]) * left[j][d] + b_out[e]
// C tile computed as C[e][j] so the f32x4 accumulator holds 4 consecutive e
// -> direct global_store_dwordx4 (contiguous in the output's fastest dim).
__global__ __launch_bounds__(256, 2)
void k_outer(const unsigned short* __restrict__ left, const float* __restrict__ Wout,
             const float* __restrict__ bout, float* __restrict__ out) {
  __shared__ __attribute__((aligned(16))) unsigned short sA[128 * LDP]; // left[j-tile][d]
  __shared__ __attribute__((aligned(16))) unsigned short sB[128 * LDP]; // B[e][d] = Wout[e][d]*left_i[d]
  __shared__ float sLi[Dd];
  __shared__ __attribute__((aligned(16))) float sBo[Dd];

  const int jt = blockIdx.x;   // 0..5
  const int i  = blockIdx.y;   // 0..767
  const int t  = threadIdx.x;  // 0..255

  if (t < Dd) {
    sLi[t] = bf2f(left[i * Dd + t]);
    sBo[t] = bout[t];
  }
  __syncthreads();

  // Stage sA (left j-tile, bf16 passthrough) and sB (scaled W_out rows -> bf16).
  {
    const int row = t >> 4;          // 0..15
    const int c8  = (t & 15) * 8;    // column chunk of 8 elems
#pragma unroll
    for (int it = 0; it < 8; ++it) {
      const int r = row + it * 16;   // 0..127
      i32x4 va = *(const i32x4*)(left + (jt * 128 + r) * Dd + c8);
      *(i32x4*)(sA + r * LDP + c8) = va;
      const float4* wp = (const float4*)(Wout + r * Dd + c8);
      float4 w0 = wp[0], w1 = wp[1];
      unsigned int p0 = (unsigned int)f2bf(w0.x * sLi[c8+0]) | ((unsigned int)f2bf(w0.y * sLi[c8+1]) << 16);
      unsigned int p1 = (unsigned int)f2bf(w0.z * sLi[c8+2]) | ((unsigned int)f2bf(w0.w * sLi[c8+3]) << 16);
      unsigned int p2 = (unsigned int)f2bf(w1.x * sLi[c8+4]) | ((unsigned int)f2bf(w1.y * sLi[c8+5]) << 16);
      unsigned int p3 = (unsigned int)f2bf(w1.z * sLi[c8+6]) | ((unsigned int)f2bf(w1.w * sLi[c8+7]) << 16);
      i32x4 vb; vb[0] = (int)p0; vb[1] = (int)p1; vb[2] = (int)p2; vb[3] = (int)p3;
      *(i32x4*)(sB + r * LDP + c8) = vb;
    }
  }
  __syncthreads();

  const int wid  = t >> 6;        // wave 0..3 -> e rows [wid*32, wid*32+32)
  const int lane = t & 63;
  const int l15  = lane & 15;
  const int kq   = (lane >> 4) * 8;  // k-offset within 32-wide k-block

  f32x4 acc[2][8] = {};   // [e-frag m][j-frag n]

#pragma unroll
  for (int kb = 0; kb < 4; ++kb) {
    const int k = kb * 32 + kq;
    // A operand = scaled-Wout rows (e), B operand = left rows (j)
    bf16x8 a0 = *(const bf16x8*)(sB + (wid * 32 +      l15) * LDP + k);
    bf16x8 a1 = *(const bf16x8*)(sB + (wid * 32 + 16 + l15) * LDP + k);
#pragma unroll
    for (int n = 0; n < 8; ++n) {
      bf16x8 b = *(const bf16x8*)(sA + (n * 16 + l15) * LDP + k);
      acc[0][n] = __builtin_amdgcn_mfma_f32_16x16x32_bf16(a0, b, acc[0][n], 0, 0, 0);
      acc[1][n] = __builtin_amdgcn_mfma_f32_16x16x32_bf16(a1, b, acc[1][n], 0, 0, 0);
    }
  }

  // Epilogue: C[e][j]; row(e) = (lane>>4)*4 + reg, col(j) = lane&15.
  // Each fragment -> one 16B store of 4 consecutive e at fixed j.
#pragma unroll
  for (int m = 0; m < 2; ++m) {
    const int e0 = wid * 32 + m * 16 + (lane >> 4) * 4;
    const f32x4 bias = *(const f32x4*)(sBo + e0);
#pragma unroll
    for (int n = 0; n < 8; ++n) {
      const int j = jt * 128 + n * 16 + l15;
      f32x4 v = acc[m][n] + bias;
      *(f32x4*)(out + ((size_t)i * Nn + j) * Dd + e0) = v;
    }
  }
}

extern "C" void kernel_launch(void* const* d_in, const int* in_sizes, int n_in,
                              void* d_out, int out_size, void* d_ws, size_t ws_size,
                              hipStream_t stream) {
  const float* x    = (const float*)d_in[0];
  const float* Win  = (const float*)d_in[1];
  const float* bin  = (const float*)d_in[2];
  const float* Wout = (const float*)d_in[3];
  const float* bout = (const float*)d_in[4];
  float* out = (float*)d_out;
  unsigned short* left = (unsigned short*)d_ws;  // 768*128 bf16 = 192 KiB

  k_left<<<Nn, Dd, 0, stream>>>(x, Win, bin, left);
  dim3 grid(Nn / 128, Nn);
  k_outer<<<grid, 256, 0, stream>>>(left, Wout, bout, out);
}

// Round 3
// 71.109 us; speedup vs baseline: 1.2768x; 1.2768x over previous
//
#include <hip/hip_runtime.h>

#define Nn 768
#define Dd 128
#define LDP 136    // padded bf16 row stride (272 B)
#define TLP 132    // padded f32 tile row stride (528 B)

typedef __attribute__((ext_vector_type(8))) short bf16x8;
typedef __attribute__((ext_vector_type(4))) float f32x4;
typedef __attribute__((ext_vector_type(4))) int   i32x4;

static __device__ __forceinline__ unsigned short f2bf(float f) {
  unsigned int u = __builtin_bit_cast(unsigned int, f);
  u += 0x7fffu + ((u >> 16) & 1u);   // RNE
  return (unsigned short)(u >> 16);
}
static __device__ __forceinline__ float bf2f(unsigned short h) {
  unsigned int u = ((unsigned int)h) << 16;
  return __builtin_bit_cast(float, u);
}

// left[i][e] = sum_d x[i][d] * W_in[e][d] + b_in[e], stored bf16
__global__ __launch_bounds__(128)
void k_left(const float* __restrict__ x, const float* __restrict__ Win,
            const float* __restrict__ bin, unsigned short* __restrict__ left) {
  __shared__ float sx[Dd];
  const int i = blockIdx.x;
  const int e = threadIdx.x;
  sx[e] = x[i * Dd + e];
  __syncthreads();
  const float4* wrow = (const float4*)(Win + e * Dd);
  float a0 = 0.f, a1 = 0.f, a2 = 0.f, a3 = 0.f;
#pragma unroll
  for (int d4 = 0; d4 < Dd / 4; d4 += 4) {
    float4 w0 = wrow[d4+0], w1 = wrow[d4+1], w2 = wrow[d4+2], w3 = wrow[d4+3];
    a0 += sx[4*d4+ 0]*w0.x + sx[4*d4+ 1]*w0.y + sx[4*d4+ 2]*w0.z + sx[4*d4+ 3]*w0.w;
    a1 += sx[4*d4+ 4]*w1.x + sx[4*d4+ 5]*w1.y + sx[4*d4+ 6]*w1.z + sx[4*d4+ 7]*w1.w;
    a2 += sx[4*d4+ 8]*w2.x + sx[4*d4+ 9]*w2.y + sx[4*d4+10]*w2.z + sx[4*d4+11]*w2.w;
    a3 += sx[4*d4+12]*w3.x + sx[4*d4+13]*w3.y + sx[4*d4+14]*w3.z + sx[4*d4+15]*w3.w;
  }
  left[i * Dd + e] = f2bf(((a0 + a1) + (a2 + a3)) + bin[e]);
}

// out[i, j, e] = sum_d (W_out[e][d] * left[i][d]) * left[j][d] + b_out[e]
// MFMA computes C[e][j] (regs = 4 consecutive e); epilogue stages the f32
// tile in LDS (aliased over sA/sB) and streams it out with fully-contiguous
// 1 KB-per-wave-instruction nontemporal stores.
__global__ __launch_bounds__(256, 2)
void k_outer(const unsigned short* __restrict__ left, const float* __restrict__ Wout,
             const float* __restrict__ bout, float* __restrict__ out) {
  // union: [phase 1] sA (128*LDP bf16) + sB (128*LDP bf16) = 69632 B
  //        [phase 2] tile (128*TLP f32) = 67584 B
  __shared__ __attribute__((aligned(16))) char smem[128 * LDP * 2 * 2];
  unsigned short* sA = (unsigned short*)smem;                    // left[j-tile][d]
  unsigned short* sB = (unsigned short*)(smem + 128 * LDP * 2);  // Wout[e][d]*left_i[d]
  float* tile = (float*)smem;                                    // out tile [j][e], stride TLP
  __shared__ float sLi[Dd];
  __shared__ __attribute__((aligned(16))) float sBo[Dd];

  const int jt = blockIdx.x;   // 0..5
  const int i  = blockIdx.y;   // 0..767
  const int t  = threadIdx.x;  // 0..255

  if (t < Dd) {
    sLi[t] = bf2f(left[i * Dd + t]);
    sBo[t] = bout[t];
  }
  __syncthreads();

  // Stage sA (left j-tile) and sB (scaled W_out rows -> bf16).
  {
    const int row = t >> 4;          // 0..15
    const int c8  = (t & 15) * 8;    // column chunk of 8 elems
#pragma unroll
    for (int it = 0; it < 8; ++it) {
      const int r = row + it * 16;   // 0..127
      i32x4 va = *(const i32x4*)(left + (jt * 128 + r) * Dd + c8);
      *(i32x4*)(sA + r * LDP + c8) = va;
      const float4* wp = (const float4*)(Wout + r * Dd + c8);
      float4 w0 = wp[0], w1 = wp[1];
      unsigned int p0 = (unsigned int)f2bf(w0.x * sLi[c8+0]) | ((unsigned int)f2bf(w0.y * sLi[c8+1]) << 16);
      unsigned int p1 = (unsigned int)f2bf(w0.z * sLi[c8+2]) | ((unsigned int)f2bf(w0.w * sLi[c8+3]) << 16);
      unsigned int p2 = (unsigned int)f2bf(w1.x * sLi[c8+4]) | ((unsigned int)f2bf(w1.y * sLi[c8+5]) << 16);
      unsigned int p3 = (unsigned int)f2bf(w1.z * sLi[c8+6]) | ((unsigned int)f2bf(w1.w * sLi[c8+7]) << 16);
      i32x4 vb; vb[0] = (int)p0; vb[1] = (int)p1; vb[2] = (int)p2; vb[3] = (int)p3;
      *(i32x4*)(sB + r * LDP + c8) = vb;
    }
  }
  __syncthreads();

  const int wid  = t >> 6;        // wave 0..3 -> e rows [wid*32, wid*32+32)
  const int lane = t & 63;
  const int l15  = lane & 15;
  const int kq   = (lane >> 4) * 8;

  f32x4 acc[2][8] = {};   // [e-frag m][j-frag n]

#pragma unroll
  for (int kb = 0; kb < 4; ++kb) {
    const int k = kb * 32 + kq;
    bf16x8 a0 = *(const bf16x8*)(sB + (wid * 32 +      l15) * LDP + k);
    bf16x8 a1 = *(const bf16x8*)(sB + (wid * 32 + 16 + l15) * LDP + k);
#pragma unroll
    for (int n = 0; n < 8; ++n) {
      bf16x8 b = *(const bf16x8*)(sA + (n * 16 + l15) * LDP + k);
      acc[0][n] = __builtin_amdgcn_mfma_f32_16x16x32_bf16(a0, b, acc[0][n], 0, 0, 0);
      acc[1][n] = __builtin_amdgcn_mfma_f32_16x16x32_bf16(a1, b, acc[1][n], 0, 0, 0);
    }
  }

  __syncthreads();  // all sA/sB reads done; smem becomes the f32 out tile

  // acc -> LDS tile[j][e] with bias (one ds_write_b128 per fragment)
#pragma unroll
  for (int m = 0; m < 2; ++m) {
    const int e0 = wid * 32 + m * 16 + (lane >> 4) * 4;
    const f32x4 bias = *(const f32x4*)(sBo + e0);
#pragma unroll
    for (int n = 0; n < 8; ++n) {
      const int j = n * 16 + l15;           // local row
      *(f32x4*)(tile + j * TLP + e0) = acc[m][n] + bias;
    }
  }
  __syncthreads();

  // Linear readback -> fully contiguous 1 KB/wave nontemporal stores.
  {
    const int row0 = t >> 5;                // 0..7
    const int col  = (t & 31) * 4;          // 0..124
    const float* tp = tile + row0 * TLP + col;
    float* op = out + ((size_t)i * Nn + jt * 128) * Dd + t * 4;
#pragma unroll
    for (int it = 0; it < 16; ++it) {
      f32x4 v = *(const f32x4*)(tp + it * 8 * TLP);       // row = row0 + it*8
      __builtin_nontemporal_store(v, (f32x4*)(op + it * 1024));
    }
  }
}

extern "C" void kernel_launch(void* const* d_in, const int* in_sizes, int n_in,
                              void* d_out, int out_size, void* d_ws, size_t ws_size,
                              hipStream_t stream) {
  const float* x    = (const float*)d_in[0];
  const float* Win  = (const float*)d_in[1];
  const float* bin  = (const float*)d_in[2];
  const float* Wout = (const float*)d_in[3];
  const float* bout = (const float*)d_in[4];
  float* out = (float*)d_out;
  unsigned short* left = (unsigned short*)d_ws;  // 768*128 bf16 = 192 KiB

  k_left<<<Nn, Dd, 0, stream>>>(x, Win, bin, left);
  dim3 grid(Nn / 128, Nn);
  k_outer<<<grid, 256, 0, stream>>>(left, Wout, bout, out);
}